// Round 8
// baseline (299.746 us; speedup 1.0000x reference)
//
#include <hip/hip_runtime.h>

typedef unsigned short u16;
typedef short bf16x8 __attribute__((ext_vector_type(8)));
typedef float f32x4 __attribute__((ext_vector_type(4)));

__device__ __forceinline__ u16 f2bf(float f) {
  union { float f; unsigned u; } c; c.f = f;
  unsigned r = (c.u + 0x7FFFu + ((c.u >> 16) & 1u)) >> 16;
  return (u16)r;
}
__device__ __forceinline__ float bf2f(u16 h) {
  union { unsigned u; float f; } c; c.u = ((unsigned)h) << 16;
  return c.f;
}
__device__ __forceinline__ void gload16(const void* g, void* l) {
  __builtin_amdgcn_global_load_lds(
      (const __attribute__((address_space(1))) unsigned*)g,
      (__attribute__((address_space(3))) unsigned*)l, 16, 0, 0);
}

// ---------------------------------------------------------------------------
// Weight prep: w_qkv [512,1536] -> wqkvT bf16 [1536,512]; w_out -> woutT [512,512]
// ---------------------------------------------------------------------------
__global__ __launch_bounds__(256) void prep_weights(
    const float* __restrict__ w_qkv, const float* __restrict__ w_out,
    u16* __restrict__ wqkvT, u16* __restrict__ woutT) {
  int i = blockIdx.x * 256 + threadIdx.x;
  const int T1 = 1536 * 512;
  if (i < T1) {
    int n = i >> 9, c = i & 511;
    wqkvT[i] = f2bf(w_qkv[(size_t)c * 1536 + n]);
  } else {
    int j = i - T1;
    int n = j >> 9, c = j & 511;
    woutT[j] = f2bf(w_out[(size_t)c * 512 + n]);
  }
}

// ---------------------------------------------------------------------------
// GroupNorm: x fp32 [32,1024,512] -> z bf16; 32 groups of 16 ch
// ---------------------------------------------------------------------------
__global__ __launch_bounds__(256) void groupnorm_k(
    const float* __restrict__ x, const float* __restrict__ scale,
    const float* __restrict__ bias, u16* __restrict__ z) {
  const int blk = blockIdx.x, b = blk >> 5, g = blk & 31;
  const float* xb = x + (size_t)b * 524288 + g * 16;
  u16* zb = z + (size_t)b * 524288 + g * 16;
  const int tid = threadIdx.x, lane = tid & 63, wid = tid >> 6;

  float4 vv[16];
  float s = 0.f, ss = 0.f;
#pragma unroll
  for (int i = 0; i < 16; ++i) {
    int e = (i * 256 + tid) * 4;
    int hw = e >> 4, j = e & 15;
    vv[i] = *(const float4*)&xb[(size_t)hw * 512 + j];
    s += vv[i].x + vv[i].y + vv[i].z + vv[i].w;
    ss += vv[i].x * vv[i].x + vv[i].y * vv[i].y + vv[i].z * vv[i].z + vv[i].w * vv[i].w;
  }
#pragma unroll
  for (int off = 32; off; off >>= 1) {
    s += __shfl_xor(s, off);
    ss += __shfl_xor(ss, off);
  }
  __shared__ float rs[4], rq[4];
  if (!lane) { rs[wid] = s; rq[wid] = ss; }
  __syncthreads();
  float S_ = rs[0] + rs[1] + rs[2] + rs[3];
  float Q_ = rq[0] + rq[1] + rq[2] + rq[3];
  const float inv_n = 1.f / 16384.f;
  float mean = S_ * inv_n;
  float var = Q_ * inv_n - mean * mean;
  float rstd = rsqrtf(var + 1e-5f);

  int j0 = (tid * 4) & 15;
  float sc0 = scale[g * 16 + j0 + 0] * rstd, sc1 = scale[g * 16 + j0 + 1] * rstd;
  float sc2 = scale[g * 16 + j0 + 2] * rstd, sc3 = scale[g * 16 + j0 + 3] * rstd;
  float bi0 = bias[g * 16 + j0 + 0] - mean * sc0, bi1 = bias[g * 16 + j0 + 1] - mean * sc1;
  float bi2 = bias[g * 16 + j0 + 2] - mean * sc2, bi3 = bias[g * 16 + j0 + 3] - mean * sc3;
#pragma unroll
  for (int i = 0; i < 16; ++i) {
    int e = (i * 256 + tid) * 4;
    int hw = e >> 4, j = e & 15;
    ushort4 o;
    o.x = f2bf(vv[i].x * sc0 + bi0);
    o.y = f2bf(vv[i].y * sc1 + bi1);
    o.z = f2bf(vv[i].z * sc2 + bi2);
    o.w = f2bf(vv[i].w * sc3 + bi3);
    *(ushort4*)&zb[(size_t)hw * 512 + j] = o;
  }
}

// ---------------------------------------------------------------------------
// Persistent 8-phase 256x256xBK64 GEMM: each block processes T output tiles
// (same m0/by, bx = bx0*T+ts) with a CONTINUOUS staging pipeline across tile
// boundaries — stage at (ts,NT-1).q0 targets (ts+1,0); prologue drain happens
// once per block. Inner phase schedule identical to round-3/7 (verified).
// EPI 0: q,k rowmajor (+bias, q scaled), v -> TRANSPOSED [b][c][p]
// EPI 2: fp32 +bias+resid
// EPI 3: P' = exp(S) bf16 + partial row-sums lsum[z][row][bx*4+wn]
// EPI 4: bf16 store of acc / (sum of 16 lsum partials)
// ---------------------------------------------------------------------------
#define QSCALE 0.04419417382415922f

template <int EPI, int T>
__global__ __launch_bounds__(512, 2) void gemm8p(
    const u16* __restrict__ A, const u16* __restrict__ Bt,
    int gx, int gxy, int N, int K,
    int sched, int sp1, int sp2,
    long long sAb, long long sBb, long long sCb,
    const float* __restrict__ bias, const float* __restrict__ resid,
    u16* __restrict__ qb, u16* __restrict__ kb, u16* __restrict__ vt,
    u16* __restrict__ outb, float* __restrict__ outf,
    float* __restrict__ lsum) {
  // XCD-locality remap (grid is always 256 = 8 XCD x 32)
  const int orig = blockIdx.x;
  const int xcd = orig & 7, jj = orig >> 3;
  int id;
  if (sched == 0) {           // row-mode: bx-groups fastest within an M-slab
    int pan = jj % gx, loc = jj / gx;
    id = (xcd * sp1 + loc) * gx + pan;
  } else {                    // batch-mode: batches pinned to XCDs
    int tile = jj % gxy, bl = jj / gxy;
    id = (xcd * sp2 + bl) * gxy + tile;
  }
  const int z = id / gxy;
  const int r2 = id - z * gxy;
  const int by = r2 / gx, bx0 = r2 - by * gx;

  const u16* Ab = A + (size_t)z * sAb;
  const u16* Bb = Bt + (size_t)z * sBb;

  __shared__ u16 As[2][2][8192];  // [buf][half][128*64]
  __shared__ u16 Bs[2][2][8192];

  const int tid = threadIdx.x;
  const int lane = tid & 63, wid = tid >> 6;
  const int wm = wid & 1, wn = wid >> 1;
  const int l15 = lane & 15, l4 = lane >> 4;
  const int m0 = by * 256;

  // staging ownership: wid 0,1 -> A h0; 2,3 -> A h1; 4,5 -> B h0; 6,7 -> B h1
  const int own_is_b = wid >> 2;
  const int own_h = (wid >> 1) & 1;
  const int prow = ((wid & 1) << 6) | lane;        // 0..127 within pair
  const int srow = prow >> 3;
  const int scol = ((prow & 7) ^ (srow & 7)) << 3; // pre-swizzled src col
  const u16* ownA = Ab + (size_t)(m0 + own_h * 128 + srow) * K + scol;
  const int ldsbase = ((wid & 1) << 6) * 8;        // ushort offset, wave-uniform

  f32x4 acc[8][4];
#pragma unroll
  for (int i = 0; i < 8; ++i)
#pragma unroll
    for (int j = 0; j < 4; ++j)
#pragma unroll
      for (int r = 0; r < 4; ++r) acc[i][j][r] = 0.f;

  const int NT = K >> 6;          // 8 or 16 (power of 2)
  const int NTm = NT - 1;
  const int ntl = (NT == 8) ? 3 : 4;
  const int G = NT * T;

  auto stage = [&](int k0, int buf, int n0t) {
    u16* l0 = (own_is_b ? &Bs[buf][own_h][0] : &As[buf][own_h][0]) + ldsbase;
    const u16* g0 = own_is_b
        ? Bb + (size_t)(n0t + own_h * 128 + srow) * K + scol + k0
        : ownA + k0;
#pragma unroll
    for (int j = 0; j < 8; ++j)
      gload16(g0 + (size_t)(j * 16) * K, l0 + j * 1024);
  };

  // prologue: global tile 0 into buf 0
  stage(0, 0, bx0 * T * 256);
  asm volatile("s_waitcnt vmcnt(0)" ::: "memory");
  __builtin_amdgcn_s_barrier();

#pragma unroll 1
  for (int ts = 0; ts < T; ++ts) {
    const int n0 = (bx0 * T + ts) * 256;
#pragma unroll 1
    for (int t = 0; t < NT; ++t) {
      const int cur = t & 1;
      const int g = ts * NT + t;
      const bool pre = (g + 1 < G);
      const u16* Ah = &As[cur][wm][0];
      const u16* Bh = &Bs[cur][wn >> 1][0];
      const int rbB = (wn & 1) << 6;
      bf16x8 bq[4][2];
#pragma unroll
      for (int q = 0; q < 4; ++q) {
        bf16x8 af[2][2];
        if (q == 0) {
#pragma unroll
          for (int i = 0; i < 4; ++i) {
            const int rr = rbB + i * 16 + l15;
            const int sw = rr & 7;
            bq[i][0] = *(const bf16x8*)&Bh[rr * 64 + ((l4 ^ sw) << 3)];
            bq[i][1] = *(const bf16x8*)&Bh[rr * 64 + (((4 + l4) ^ sw) << 3)];
          }
        }
#pragma unroll
        for (int j = 0; j < 2; ++j) {
          const int rr = (q * 2 + j) * 16 + l15;
          const int sw = rr & 7;
          af[j][0] = *(const bf16x8*)&Ah[rr * 64 + ((l4 ^ sw) << 3)];
          af[j][1] = *(const bf16x8*)&Ah[rr * 64 + (((4 + l4) ^ sw) << 3)];
        }
        if (q == 0 && pre) {
          const int gn = g + 1;
          const int tn = gn & NTm;
          const int tsn = gn >> ntl;
          stage(tn << 6, cur ^ 1, (bx0 * T + tsn) * 256);
        }
        __builtin_amdgcn_s_barrier();
        asm volatile("s_waitcnt lgkmcnt(0)" ::: "memory");
        __builtin_amdgcn_sched_barrier(0);
        __builtin_amdgcn_s_setprio(1);
#pragma unroll
        for (int j = 0; j < 2; ++j)
#pragma unroll
          for (int ni = 0; ni < 4; ++ni) {
            acc[q * 2 + j][ni] = __builtin_amdgcn_mfma_f32_16x16x32_bf16(
                af[j][0], bq[ni][0], acc[q * 2 + j][ni], 0, 0, 0);
            acc[q * 2 + j][ni] = __builtin_amdgcn_mfma_f32_16x16x32_bf16(
                af[j][1], bq[ni][1], acc[q * 2 + j][ni], 0, 0, 0);
          }
        __builtin_amdgcn_s_setprio(0);
        if (q == 3 && pre) asm volatile("s_waitcnt vmcnt(0)" ::: "memory");
        __builtin_amdgcn_s_barrier();
      }
    }

    // ---------------- epilogue for sub-tile ts ----------------
    const int bx = bx0 * T + ts;
    if (EPI == 0) {
#pragma unroll
      for (int mi = 0; mi < 8; ++mi) {
#pragma unroll
        for (int ni = 0; ni < 4; ++ni) {
          const int gr0 = m0 + wm * 128 + mi * 16 + l4 * 4;
          const int gc = n0 + wn * 64 + ni * 16 + l15;
          const int bsel = gc >> 9, cin = gc & 511;
          const float bs = bias[gc];
          if (bsel < 2) {
            u16* dst = bsel ? kb : qb;
#pragma unroll
            for (int r = 0; r < 4; ++r) {
              float vvv = acc[mi][ni][r] + bs;
              if (bsel == 0) vvv *= QSCALE;
              dst[(size_t)(gr0 + r) * 512 + cin] = f2bf(vvv);
            }
          } else {
            ushort4 o;
            o.x = f2bf(acc[mi][ni][0] + bs);
            o.y = f2bf(acc[mi][ni][1] + bs);
            o.z = f2bf(acc[mi][ni][2] + bs);
            o.w = f2bf(acc[mi][ni][3] + bs);
            const int bb = gr0 >> 10, p = gr0 & 1023;
            *(ushort4*)&vt[(size_t)bb * 524288 + (size_t)cin * 1024 + p] = o;
          }
        }
      }
    } else if (EPI == 2) {
#pragma unroll
      for (int mi = 0; mi < 8; ++mi) {
#pragma unroll
        for (int ni = 0; ni < 4; ++ni) {
          const int gr0 = m0 + wm * 128 + mi * 16 + l4 * 4;
          const int gc = n0 + wn * 64 + ni * 16 + l15;
#pragma unroll
          for (int r = 0; r < 4; ++r)
            outf[(size_t)(gr0 + r) * N + gc] =
                acc[mi][ni][r] + bias[gc] + resid[(size_t)(gr0 + r) * N + gc];
        }
      }
    } else if (EPI == 3) {
      float rs_[8][4];
#pragma unroll
      for (int mi = 0; mi < 8; ++mi)
#pragma unroll
        for (int r = 0; r < 4; ++r) rs_[mi][r] = 0.f;
#pragma unroll
      for (int mi = 0; mi < 8; ++mi) {
        const int gr0 = m0 + wm * 128 + mi * 16 + l4 * 4;
#pragma unroll
        for (int ni = 0; ni < 4; ++ni) {
          const int gc = n0 + wn * 64 + ni * 16 + l15;
#pragma unroll
          for (int r = 0; r < 4; ++r) {
            float e = __expf(acc[mi][ni][r]);
            rs_[mi][r] += e;
            outb[(size_t)z * sCb + (size_t)(gr0 + r) * N + gc] = f2bf(e);
          }
        }
      }
#pragma unroll
      for (int mi = 0; mi < 8; ++mi) {
        const int gr0 = m0 + wm * 128 + mi * 16 + l4 * 4;
#pragma unroll
        for (int r = 0; r < 4; ++r) {
          float v = rs_[mi][r];
          v += __shfl_xor(v, 1);
          v += __shfl_xor(v, 2);
          v += __shfl_xor(v, 4);
          v += __shfl_xor(v, 8);
          if (l15 == 0)
            lsum[((size_t)z * 1024 + gr0 + r) * 16 + bx * 4 + wn] = v;
        }
      }
    } else {  // EPI == 4
#pragma unroll
      for (int mi = 0; mi < 8; ++mi) {
        const int gr0 = m0 + wm * 128 + mi * 16 + l4 * 4;
        float inv[4];
#pragma unroll
        for (int r = 0; r < 4; ++r) {
          const float* lp = &lsum[((size_t)z * 1024 + gr0 + r) * 16];
          const float4 a0 = *(const float4*)&lp[0];
          const float4 a1 = *(const float4*)&lp[4];
          const float4 a2 = *(const float4*)&lp[8];
          const float4 a3 = *(const float4*)&lp[12];
          inv[r] = 1.0f / (a0.x + a0.y + a0.z + a0.w + a1.x + a1.y + a1.z + a1.w +
                           a2.x + a2.y + a2.z + a2.w + a3.x + a3.y + a3.z + a3.w);
        }
#pragma unroll
        for (int ni = 0; ni < 4; ++ni) {
          const int gc = n0 + wn * 64 + ni * 16 + l15;
#pragma unroll
          for (int r = 0; r < 4; ++r)
            outb[(size_t)z * sCb + (size_t)(gr0 + r) * N + gc] =
                f2bf(acc[mi][ni][r] * inv[r]);
        }
      }
    }

    // reset accumulators for next sub-tile
    if (ts + 1 < T) {
#pragma unroll
      for (int i = 0; i < 8; ++i)
#pragma unroll
        for (int j = 0; j < 4; ++j)
#pragma unroll
          for (int r = 0; r < 4; ++r) acc[i][j][r] = 0.f;
    }
  }
}

// ---------------------------------------------------------------------------
extern "C" void kernel_launch(void* const* d_in, const int* in_sizes, int n_in,
                              void* d_out, int out_size, void* d_ws, size_t ws_size,
                              hipStream_t stream) {
  const float* x = (const float*)d_in[0];
  const float* gn_scale = (const float*)d_in[2];
  const float* gn_bias = (const float*)d_in[3];
  const float* w_qkv = (const float*)d_in[4];
  const float* b_qkv = (const float*)d_in[5];
  const float* w_out = (const float*)d_in[6];
  const float* b_out = (const float*)d_in[7];
  float* out = (float*)d_out;

  char* ws = (char*)d_ws;
  const size_t MB = 1024ull * 1024ull;
  u16* qb = (u16*)(ws + 0 * MB);      // 32 MB  [32768][512]
  u16* kb = (u16*)(ws + 32 * MB);     // 32 MB  [32768][512]
  u16* vt = (u16*)(ws + 64 * MB);     // 32 MB  [32][512][1024]  (V transposed)
  float* lsum = (float*)(ws + 96 * MB); // 2 MB [32][1024][16] partial row sums
  u16* zO = (u16*)(ws + 128 * MB);    // 32 MB  z, later reused as O
  u16* S = (u16*)(ws + 160 * MB);     // 64 MB  [32][1024][1024] (P' = exp(S))
  u16* wqkvT = (u16*)(ws + 224 * MB); // 1.5 MB [1536][512]
  u16* woutT = (u16*)(ws + 226 * MB); // 0.5 MB [512][512]

  prep_weights<<<4096, 256, 0, stream>>>(w_qkv, w_out, wqkvT, woutT);
  groupnorm_k<<<1024, 256, 0, stream>>>(x, gn_scale, gn_bias, zO);

  // QKV: z @ wqkvT^T -> q,k (rowmajor, q scaled), v (transposed)
  // persistent T=3: 256 blocks, each 3 n-panels; row-mode, sp1=16
  gemm8p<0, 3><<<256, 512, 0, stream>>>(
      zO, wqkvT, 2, 256, 1536, 512, 0, 16, 0, 0, 0, 0, b_qkv, nullptr,
      qb, kb, vt, nullptr, nullptr, nullptr);

  // P' = exp(q @ k^T) + partial row sums; persistent T=2: 256 blocks
  // batch-mode: 4 batches per XCD (gxy=8 tiles of (4by x 2bxg))
  gemm8p<3, 2><<<256, 512, 0, stream>>>(
      qb, kb, 2, 8, 1024, 512, 1, 0, 4, 1024 * 512, 1024 * 512, 1024 * 1024,
      nullptr, nullptr, nullptr, nullptr, nullptr, S, nullptr, lsum);

  // O = (P' @ V) / rowsum; T=1: 256 blocks, batch-mode
  gemm8p<4, 1><<<256, 512, 0, stream>>>(
      S, vt, 2, 8, 512, 1024, 1, 0, 4, 1024 * 1024, 512 * 1024, 1024 * 512,
      nullptr, nullptr, nullptr, nullptr, nullptr, zO, nullptr, lsum);

  // out = O @ w_out^T + b_out + x; T=1: 256 blocks, row-mode
  gemm8p<2, 1><<<256, 512, 0, stream>>>(
      zO, woutT, 2, 256, 512, 512, 0, 16, 0, 0, 0, 0, b_out, x,
      nullptr, nullptr, nullptr, nullptr, out, nullptr);
}

// Round 9
// 271.048 us; speedup vs baseline: 1.1059x; 1.1059x over previous
//
#include <hip/hip_runtime.h>

typedef unsigned short u16;
typedef short bf16x8 __attribute__((ext_vector_type(8)));
typedef float f32x4 __attribute__((ext_vector_type(4)));

__device__ __forceinline__ u16 f2bf(float f) {
  union { float f; unsigned u; } c; c.f = f;
  unsigned r = (c.u + 0x7FFFu + ((c.u >> 16) & 1u)) >> 16;
  return (u16)r;
}
__device__ __forceinline__ float bf2f(u16 h) {
  union { unsigned u; float f; } c; c.u = ((unsigned)h) << 16;
  return c.f;
}
__device__ __forceinline__ void gload16(const void* g, void* l) {
  __builtin_amdgcn_global_load_lds(
      (const __attribute__((address_space(1))) unsigned*)g,
      (__attribute__((address_space(3))) unsigned*)l, 16, 0, 0);
}

// ---------------------------------------------------------------------------
// Weight prep: w_qkv [512,1536] -> wqkvT bf16 [1536,512]; w_out -> woutT [512,512]
// ---------------------------------------------------------------------------
__global__ __launch_bounds__(256) void prep_weights(
    const float* __restrict__ w_qkv, const float* __restrict__ w_out,
    u16* __restrict__ wqkvT, u16* __restrict__ woutT) {
  int i = blockIdx.x * 256 + threadIdx.x;
  const int T1 = 1536 * 512;
  if (i < T1) {
    int n = i >> 9, c = i & 511;
    wqkvT[i] = f2bf(w_qkv[(size_t)c * 1536 + n]);
  } else {
    int j = i - T1;
    int n = j >> 9, c = j & 511;
    woutT[j] = f2bf(w_out[(size_t)c * 512 + n]);
  }
}

// ---------------------------------------------------------------------------
// GroupNorm: x fp32 [32,1024,512] -> z bf16; 32 groups of 16 ch
// ---------------------------------------------------------------------------
__global__ __launch_bounds__(256) void groupnorm_k(
    const float* __restrict__ x, const float* __restrict__ scale,
    const float* __restrict__ bias, u16* __restrict__ z) {
  const int blk = blockIdx.x, b = blk >> 5, g = blk & 31;
  const float* xb = x + (size_t)b * 524288 + g * 16;
  u16* zb = z + (size_t)b * 524288 + g * 16;
  const int tid = threadIdx.x, lane = tid & 63, wid = tid >> 6;

  float4 vv[16];
  float s = 0.f, ss = 0.f;
#pragma unroll
  for (int i = 0; i < 16; ++i) {
    int e = (i * 256 + tid) * 4;
    int hw = e >> 4, j = e & 15;
    vv[i] = *(const float4*)&xb[(size_t)hw * 512 + j];
    s += vv[i].x + vv[i].y + vv[i].z + vv[i].w;
    ss += vv[i].x * vv[i].x + vv[i].y * vv[i].y + vv[i].z * vv[i].z + vv[i].w * vv[i].w;
  }
#pragma unroll
  for (int off = 32; off; off >>= 1) {
    s += __shfl_xor(s, off);
    ss += __shfl_xor(ss, off);
  }
  __shared__ float rs[4], rq[4];
  if (!lane) { rs[wid] = s; rq[wid] = ss; }
  __syncthreads();
  float S_ = rs[0] + rs[1] + rs[2] + rs[3];
  float Q_ = rq[0] + rq[1] + rq[2] + rq[3];
  const float inv_n = 1.f / 16384.f;
  float mean = S_ * inv_n;
  float var = Q_ * inv_n - mean * mean;
  float rstd = rsqrtf(var + 1e-5f);

  int j0 = (tid * 4) & 15;
  float sc0 = scale[g * 16 + j0 + 0] * rstd, sc1 = scale[g * 16 + j0 + 1] * rstd;
  float sc2 = scale[g * 16 + j0 + 2] * rstd, sc3 = scale[g * 16 + j0 + 3] * rstd;
  float bi0 = bias[g * 16 + j0 + 0] - mean * sc0, bi1 = bias[g * 16 + j0 + 1] - mean * sc1;
  float bi2 = bias[g * 16 + j0 + 2] - mean * sc2, bi3 = bias[g * 16 + j0 + 3] - mean * sc3;
#pragma unroll
  for (int i = 0; i < 16; ++i) {
    int e = (i * 256 + tid) * 4;
    int hw = e >> 4, j = e & 15;
    ushort4 o;
    o.x = f2bf(vv[i].x * sc0 + bi0);
    o.y = f2bf(vv[i].y * sc1 + bi1);
    o.z = f2bf(vv[i].z * sc2 + bi2);
    o.w = f2bf(vv[i].w * sc3 + bi3);
    *(ushort4*)&zb[(size_t)hw * 512 + j] = o;
  }
}

// ---------------------------------------------------------------------------
// Deep-ring GEMM: C[M,N] = A[M,K] @ Bt[N,K]^T.  256x256 tile, BK=32,
// 4-buffer LDS ring (A,B: 4 x 16KB each = 128KB).  512 thr = 8 waves (2Mx4N),
// per-wave 128x64 C, acc[8][4].  Per BK32-tile: stage 4 sweeps for tile t+3
// (1 gload16/thread each), 12 ds_read_b128 (bq 4 + af 8, swizzled 2-way-free),
// 32 MFMA in two setprio clusters, ONE counted vmcnt(8) + ONE s_barrier.
// Waited staging loads are >=4 phases old; compiler auto-handles lgkmcnt.
// LDS layout per buf half: [64 ldsrows][128B], granule g' = g ^ (ldsrow&7);
// staging source pre-applies the same involution (verified inverse).
// EPI 0: q,k rowmajor (+bias, q scaled), v -> TRANSPOSED [b][c][p]
// EPI 2: fp32 +bias+resid
// EPI 3: P' = exp(S) bf16 + partial row-sums lsum[z][row][bx*4+wn]
// EPI 4: bf16 store of acc / (sum of 16 lsum partials)
// ---------------------------------------------------------------------------
#define QSCALE 0.04419417382415922f

template <int EPI>
__global__ __launch_bounds__(512, 2) void gemm_ring(
    const u16* __restrict__ A, const u16* __restrict__ Bt,
    int gx, int gxy, int N, int K,
    int sched, int sp1, int sp2,
    long long sAb, long long sBb, long long sCb,
    const float* __restrict__ bias, const float* __restrict__ resid,
    u16* __restrict__ qb, u16* __restrict__ kb, u16* __restrict__ vt,
    u16* __restrict__ outb, float* __restrict__ outf,
    float* __restrict__ lsum) {
  // XCD-locality remap
  const int orig = blockIdx.x;
  const int xcd = orig & 7, jj = orig >> 3;
  int id;
  if (sched == 0) {
    int pan = jj % gx, loc = jj / gx;
    id = (xcd * sp1 + loc) * gx + pan;
  } else {
    int tile = jj % gxy, bl = jj / gxy;
    id = (xcd * sp2 + bl) * gxy + tile;
  }
  const int z = id / gxy;
  const int r2 = id - z * gxy;
  const int by = r2 / gx, bx = r2 - by * gx;

  const u16* Ab = A + (size_t)z * sAb;
  const u16* Bb = Bt + (size_t)z * sBb;

  __shared__ u16 As[4][8192];  // [buf][half(2) x 64 ldsrows x 64 u16]
  __shared__ u16 Bs[4][8192];

  const int tid = threadIdx.x;
  const int lane = tid & 63, wid = tid >> 6;
  const int wm = wid & 1, wn = wid >> 1;
  const int l15 = lane & 15, l4 = lane >> 4;
  const int m0 = by * 256, n0 = bx * 256;

  // staging map: thread -> (ldsrow, granule) -> pre-swizzled source (row, k)
  const int lrs = tid >> 3;                 // ldsrow 0..63
  const int g0 = (tid & 7) ^ (lrs & 7);     // source granule (involution)
  const int ra = (lrs << 1) | (g0 >> 2);    // source tile-row 0..127
  const int ko = (g0 & 3) << 3;             // source k offset 0/8/16/24

  // fragment-read bases (u16 offsets), swizzle folded to per-thread constant
  const int lrb = l15 >> 1;
  const int gg = ((l15 & 1) << 2) | l4;
  const int gsw = gg ^ lrb;
  const int aoff = wm * 4096 + lrb * 64 + gsw * 8;                      // + mi*512
  const int boff = (wn >> 1) * 4096 + (wn & 1) * 2048 + lrb * 64 + gsw * 8;  // + ni*512

  f32x4 acc[8][4];
#pragma unroll
  for (int i = 0; i < 8; ++i)
#pragma unroll
    for (int j = 0; j < 4; ++j)
#pragma unroll
      for (int r = 0; r < 4; ++r) acc[i][j][r] = 0.f;

  const int NT = K >> 5;  // 16 or 32

  auto stA = [&](int sb, int t2) {
    const u16* s0 = Ab + (size_t)(m0 + ra) * K + t2 * 32 + ko;
    const u16* s1 = Ab + (size_t)(m0 + 128 + ra) * K + t2 * 32 + ko;
    gload16(s0, &As[sb][tid * 8]);
    gload16(s1, &As[sb][4096 + tid * 8]);
  };
  auto stB = [&](int sb, int t2) {
    const u16* s0 = Bb + (size_t)(n0 + ra) * K + t2 * 32 + ko;
    const u16* s1 = Bb + (size_t)(n0 + 128 + ra) * K + t2 * 32 + ko;
    gload16(s0, &Bs[sb][tid * 8]);
    gload16(s1, &Bs[sb][4096 + tid * 8]);
  };

#define TILE_BODY(P, TT, DOSTG, WN)                                            \
  do {                                                                         \
    if (DOSTG) { stA(((P) + 3) & 3, (TT) + 3); stB(((P) + 3) & 3, (TT) + 3); } \
    bf16x8 bq[4], af0[4], af1[4];                                              \
    _Pragma("unroll") for (int ni = 0; ni < 4; ++ni)                           \
        bq[ni] = *(const bf16x8*)&Bs[P][boff + ni * 512];                      \
    _Pragma("unroll") for (int i = 0; i < 4; ++i)                              \
        af0[i] = *(const bf16x8*)&As[P][aoff + i * 512];                       \
    _Pragma("unroll") for (int i = 0; i < 4; ++i)                              \
        af1[i] = *(const bf16x8*)&As[P][aoff + 2048 + i * 512];                \
    __builtin_amdgcn_s_setprio(1);                                             \
    _Pragma("unroll") for (int i = 0; i < 4; ++i)                              \
        _Pragma("unroll") for (int ni = 0; ni < 4; ++ni)                       \
            acc[i][ni] = __builtin_amdgcn_mfma_f32_16x16x32_bf16(              \
                af0[i], bq[ni], acc[i][ni], 0, 0, 0);                          \
    _Pragma("unroll") for (int i = 0; i < 4; ++i)                              \
        _Pragma("unroll") for (int ni = 0; ni < 4; ++ni)                       \
            acc[4 + i][ni] = __builtin_amdgcn_mfma_f32_16x16x32_bf16(          \
                af1[i], bq[ni], acc[4 + i][ni], 0, 0, 0);                      \
    __builtin_amdgcn_s_setprio(0);                                             \
    if ((WN) == 8) asm volatile("s_waitcnt vmcnt(8)" ::: "memory");            \
    else if ((WN) == 4) asm volatile("s_waitcnt vmcnt(4)" ::: "memory");       \
    else if ((WN) == 0) asm volatile("s_waitcnt vmcnt(0)" ::: "memory");       \
    if ((WN) >= -1) __builtin_amdgcn_s_barrier();                              \
  } while (0)

  // prologue: tiles 0,1,2 staged; wait tile 0 (leave tiles 1,2 = 8 in flight)
  stA(0, 0); stB(0, 0);
  stA(1, 1); stB(1, 1);
  stA(2, 2); stB(2, 2);
  asm volatile("s_waitcnt vmcnt(8)" ::: "memory");
  __builtin_amdgcn_s_barrier();

  int t = 0;
  for (; t + 7 < NT; t += 4) {
    TILE_BODY(0, t, 1, 8);
    TILE_BODY(1, t + 1, 1, 8);
    TILE_BODY(2, t + 2, 1, 8);
    TILE_BODY(3, t + 3, 1, 8);
  }
  // tail: t == NT-4
  TILE_BODY(0, t, 1, 8);        // stages NT-1
  TILE_BODY(1, t + 1, 0, 4);
  TILE_BODY(2, t + 2, 0, 0);
  TILE_BODY(3, t + 3, 0, -2);   // no wait, no barrier

#undef TILE_BODY

  // ---------------- epilogues ----------------
  if (EPI == 0) {
#pragma unroll
    for (int mi = 0; mi < 8; ++mi) {
#pragma unroll
      for (int ni = 0; ni < 4; ++ni) {
        const int gr0 = m0 + wm * 128 + mi * 16 + l4 * 4;
        const int gc = n0 + wn * 64 + ni * 16 + l15;
        const int bsel = gc >> 9, cin = gc & 511;
        const float bs = bias[gc];
        if (bsel < 2) {
          u16* dst = bsel ? kb : qb;
#pragma unroll
          for (int r = 0; r < 4; ++r) {
            float vvv = acc[mi][ni][r] + bs;
            if (bsel == 0) vvv *= QSCALE;
            dst[(size_t)(gr0 + r) * 512 + cin] = f2bf(vvv);
          }
        } else {
          ushort4 o;
          o.x = f2bf(acc[mi][ni][0] + bs);
          o.y = f2bf(acc[mi][ni][1] + bs);
          o.z = f2bf(acc[mi][ni][2] + bs);
          o.w = f2bf(acc[mi][ni][3] + bs);
          const int bb = gr0 >> 10, p = gr0 & 1023;
          *(ushort4*)&vt[(size_t)bb * 524288 + (size_t)cin * 1024 + p] = o;
        }
      }
    }
  } else if (EPI == 2) {
#pragma unroll
    for (int mi = 0; mi < 8; ++mi) {
#pragma unroll
      for (int ni = 0; ni < 4; ++ni) {
        const int gr0 = m0 + wm * 128 + mi * 16 + l4 * 4;
        const int gc = n0 + wn * 64 + ni * 16 + l15;
#pragma unroll
        for (int r = 0; r < 4; ++r)
          outf[(size_t)(gr0 + r) * N + gc] =
              acc[mi][ni][r] + bias[gc] + resid[(size_t)(gr0 + r) * N + gc];
      }
    }
  } else if (EPI == 3) {
    float rs_[8][4];
#pragma unroll
    for (int mi = 0; mi < 8; ++mi)
#pragma unroll
      for (int r = 0; r < 4; ++r) rs_[mi][r] = 0.f;
#pragma unroll
    for (int mi = 0; mi < 8; ++mi) {
      const int gr0 = m0 + wm * 128 + mi * 16 + l4 * 4;
#pragma unroll
      for (int ni = 0; ni < 4; ++ni) {
        const int gc = n0 + wn * 64 + ni * 16 + l15;
#pragma unroll
        for (int r = 0; r < 4; ++r) {
          float e = __expf(acc[mi][ni][r]);
          rs_[mi][r] += e;
          outb[(size_t)z * sCb + (size_t)(gr0 + r) * N + gc] = f2bf(e);
        }
      }
    }
#pragma unroll
    for (int mi = 0; mi < 8; ++mi) {
      const int gr0 = m0 + wm * 128 + mi * 16 + l4 * 4;
#pragma unroll
      for (int r = 0; r < 4; ++r) {
        float v = rs_[mi][r];
        v += __shfl_xor(v, 1);
        v += __shfl_xor(v, 2);
        v += __shfl_xor(v, 4);
        v += __shfl_xor(v, 8);
        if (l15 == 0)
          lsum[((size_t)z * 1024 + gr0 + r) * 16 + bx * 4 + wn] = v;
      }
    }
  } else {  // EPI == 4
#pragma unroll
    for (int mi = 0; mi < 8; ++mi) {
      const int gr0 = m0 + wm * 128 + mi * 16 + l4 * 4;
      float inv[4];
#pragma unroll
      for (int r = 0; r < 4; ++r) {
        const float* lp = &lsum[((size_t)z * 1024 + gr0 + r) * 16];
        const float4 a0 = *(const float4*)&lp[0];
        const float4 a1 = *(const float4*)&lp[4];
        const float4 a2 = *(const float4*)&lp[8];
        const float4 a3 = *(const float4*)&lp[12];
        inv[r] = 1.0f / (a0.x + a0.y + a0.z + a0.w + a1.x + a1.y + a1.z + a1.w +
                         a2.x + a2.y + a2.z + a2.w + a3.x + a3.y + a3.z + a3.w);
      }
#pragma unroll
      for (int ni = 0; ni < 4; ++ni) {
        const int gc = n0 + wn * 64 + ni * 16 + l15;
#pragma unroll
        for (int r = 0; r < 4; ++r)
          outb[(size_t)z * sCb + (size_t)(gr0 + r) * N + gc] =
              f2bf(acc[mi][ni][r] * inv[r]);
      }
    }
  }
}

// ---------------------------------------------------------------------------
extern "C" void kernel_launch(void* const* d_in, const int* in_sizes, int n_in,
                              void* d_out, int out_size, void* d_ws, size_t ws_size,
                              hipStream_t stream) {
  const float* x = (const float*)d_in[0];
  const float* gn_scale = (const float*)d_in[2];
  const float* gn_bias = (const float*)d_in[3];
  const float* w_qkv = (const float*)d_in[4];
  const float* b_qkv = (const float*)d_in[5];
  const float* w_out = (const float*)d_in[6];
  const float* b_out = (const float*)d_in[7];
  float* out = (float*)d_out;

  char* ws = (char*)d_ws;
  const size_t MB = 1024ull * 1024ull;
  u16* qb = (u16*)(ws + 0 * MB);      // 32 MB  [32768][512]
  u16* kb = (u16*)(ws + 32 * MB);     // 32 MB  [32768][512]
  u16* vt = (u16*)(ws + 64 * MB);     // 32 MB  [32][512][1024]  (V transposed)
  float* lsum = (float*)(ws + 96 * MB); // 2 MB [32][1024][16] partial row sums
  u16* zO = (u16*)(ws + 128 * MB);    // 32 MB  z, later reused as O
  u16* S = (u16*)(ws + 160 * MB);     // 64 MB  [32][1024][1024] (P' = exp(S))
  u16* wqkvT = (u16*)(ws + 224 * MB); // 1.5 MB [1536][512]
  u16* woutT = (u16*)(ws + 226 * MB); // 0.5 MB [512][512]

  prep_weights<<<4096, 256, 0, stream>>>(w_qkv, w_out, wqkvT, woutT);
  groupnorm_k<<<1024, 256, 0, stream>>>(x, gn_scale, gn_bias, zO);

  // QKV: z @ wqkvT^T -> q,k (rowmajor, q scaled), v (transposed)
  gemm_ring<0><<<768, 512, 0, stream>>>(
      zO, wqkvT, 6, 768, 1536, 512, 0, 16, 0, 0, 0, 0, b_qkv, nullptr,
      qb, kb, vt, nullptr, nullptr, nullptr);

  // P' = exp(q @ k^T) (batched over 32) + partial row sums
  gemm_ring<3><<<512, 512, 0, stream>>>(
      qb, kb, 4, 16, 1024, 512, 1, 0, 4, 1024 * 512, 1024 * 512, 1024 * 1024,
      nullptr, nullptr, nullptr, nullptr, nullptr, S, nullptr, lsum);

  // O = (P' @ V) / rowsum   (vt is [512][1024] per batch)
  gemm_ring<4><<<256, 512, 0, stream>>>(
      S, vt, 2, 8, 512, 1024, 1, 0, 4, 1024 * 1024, 512 * 1024, 1024 * 512,
      nullptr, nullptr, nullptr, nullptr, nullptr, zO, nullptr, lsum);

  // out = O @ w_out^T + b_out + x
  gemm_ring<2><<<256, 512, 0, stream>>>(
      zO, woutT, 2, 256, 512, 512, 0, 16, 0, 0, 0, 0, b_out, x,
      nullptr, nullptr, nullptr, nullptr, out, nullptr);
}

// Round 10
// 257.921 us; speedup vs baseline: 1.1622x; 1.0509x over previous
//
#include <hip/hip_runtime.h>

typedef unsigned short u16;
typedef short bf16x8 __attribute__((ext_vector_type(8)));
typedef float f32x4 __attribute__((ext_vector_type(4)));

__device__ __forceinline__ u16 f2bf(float f) {
  union { float f; unsigned u; } c; c.f = f;
  unsigned r = (c.u + 0x7FFFu + ((c.u >> 16) & 1u)) >> 16;
  return (u16)r;
}
__device__ __forceinline__ float bf2f(u16 h) {
  union { unsigned u; float f; } c; c.u = ((unsigned)h) << 16;
  return c.f;
}
__device__ __forceinline__ void gload16(const void* g, void* l) {
  __builtin_amdgcn_global_load_lds(
      (const __attribute__((address_space(1))) unsigned*)g,
      (__attribute__((address_space(3))) unsigned*)l, 16, 0, 0);
}

// ---------------------------------------------------------------------------
// Weight prep: w_qkv [512,1536] -> wqkvT bf16 [1536,512]; w_out -> woutT [512,512]
// ---------------------------------------------------------------------------
__global__ __launch_bounds__(256) void prep_weights(
    const float* __restrict__ w_qkv, const float* __restrict__ w_out,
    u16* __restrict__ wqkvT, u16* __restrict__ woutT) {
  int i = blockIdx.x * 256 + threadIdx.x;
  const int T1 = 1536 * 512;
  if (i < T1) {
    int n = i >> 9, c = i & 511;
    wqkvT[i] = f2bf(w_qkv[(size_t)c * 1536 + n]);
  } else {
    int j = i - T1;
    int n = j >> 9, c = j & 511;
    woutT[j] = f2bf(w_out[(size_t)c * 512 + n]);
  }
}

// ---------------------------------------------------------------------------
// GroupNorm: x fp32 [32,1024,512] -> z bf16; 32 groups of 16 ch
// ---------------------------------------------------------------------------
__global__ __launch_bounds__(256) void groupnorm_k(
    const float* __restrict__ x, const float* __restrict__ scale,
    const float* __restrict__ bias, u16* __restrict__ z) {
  const int blk = blockIdx.x, b = blk >> 5, g = blk & 31;
  const float* xb = x + (size_t)b * 524288 + g * 16;
  u16* zb = z + (size_t)b * 524288 + g * 16;
  const int tid = threadIdx.x, lane = tid & 63, wid = tid >> 6;

  float4 vv[16];
  float s = 0.f, ss = 0.f;
#pragma unroll
  for (int i = 0; i < 16; ++i) {
    int e = (i * 256 + tid) * 4;
    int hw = e >> 4, j = e & 15;
    vv[i] = *(const float4*)&xb[(size_t)hw * 512 + j];
    s += vv[i].x + vv[i].y + vv[i].z + vv[i].w;
    ss += vv[i].x * vv[i].x + vv[i].y * vv[i].y + vv[i].z * vv[i].z + vv[i].w * vv[i].w;
  }
#pragma unroll
  for (int off = 32; off; off >>= 1) {
    s += __shfl_xor(s, off);
    ss += __shfl_xor(ss, off);
  }
  __shared__ float rs[4], rq[4];
  if (!lane) { rs[wid] = s; rq[wid] = ss; }
  __syncthreads();
  float S_ = rs[0] + rs[1] + rs[2] + rs[3];
  float Q_ = rq[0] + rq[1] + rq[2] + rq[3];
  const float inv_n = 1.f / 16384.f;
  float mean = S_ * inv_n;
  float var = Q_ * inv_n - mean * mean;
  float rstd = rsqrtf(var + 1e-5f);

  int j0 = (tid * 4) & 15;
  float sc0 = scale[g * 16 + j0 + 0] * rstd, sc1 = scale[g * 16 + j0 + 1] * rstd;
  float sc2 = scale[g * 16 + j0 + 2] * rstd, sc3 = scale[g * 16 + j0 + 3] * rstd;
  float bi0 = bias[g * 16 + j0 + 0] - mean * sc0, bi1 = bias[g * 16 + j0 + 1] - mean * sc1;
  float bi2 = bias[g * 16 + j0 + 2] - mean * sc2, bi3 = bias[g * 16 + j0 + 3] - mean * sc3;
#pragma unroll
  for (int i = 0; i < 16; ++i) {
    int e = (i * 256 + tid) * 4;
    int hw = e >> 4, j = e & 15;
    ushort4 o;
    o.x = f2bf(vv[i].x * sc0 + bi0);
    o.y = f2bf(vv[i].y * sc1 + bi1);
    o.z = f2bf(vv[i].z * sc2 + bi2);
    o.w = f2bf(vv[i].w * sc3 + bi3);
    *(ushort4*)&zb[(size_t)hw * 512 + j] = o;
  }
}

// ---------------------------------------------------------------------------
// Deep-ring GEMM (round-9, unchanged inner loop): 256x256 tile, BK=32,
// 4-buffer LDS ring, 1 barrier + counted vmcnt(8) per tile.
// EPI 0: q,k rowmajor (+bias, q scaled), v -> TRANSPOSED [b][c][p]
// EPI 2: fp32 +bias+resid
// ---------------------------------------------------------------------------
#define QSCALE 0.04419417382415922f

template <int EPI>
__global__ __launch_bounds__(512, 2) void gemm_ring(
    const u16* __restrict__ A, const u16* __restrict__ Bt,
    int gx, int gxy, int N, int K,
    int sched, int sp1, int sp2,
    long long sAb, long long sBb, long long sCb,
    const float* __restrict__ bias, const float* __restrict__ resid,
    u16* __restrict__ qb, u16* __restrict__ kb, u16* __restrict__ vt,
    u16* __restrict__ outb, float* __restrict__ outf) {
  const int orig = blockIdx.x;
  const int xcd = orig & 7, jj = orig >> 3;
  int id;
  if (sched == 0) {
    int pan = jj % gx, loc = jj / gx;
    id = (xcd * sp1 + loc) * gx + pan;
  } else {
    int tile = jj % gxy, bl = jj / gxy;
    id = (xcd * sp2 + bl) * gxy + tile;
  }
  const int z = id / gxy;
  const int r2 = id - z * gxy;
  const int by = r2 / gx, bx = r2 - by * gx;

  const u16* Ab = A + (size_t)z * sAb;
  const u16* Bb = Bt + (size_t)z * sBb;

  __shared__ u16 As[4][8192];
  __shared__ u16 Bs[4][8192];

  const int tid = threadIdx.x;
  const int lane = tid & 63, wid = tid >> 6;
  const int wm = wid & 1, wn = wid >> 1;
  const int l15 = lane & 15, l4 = lane >> 4;
  const int m0 = by * 256, n0 = bx * 256;

  const int lrs = tid >> 3;
  const int g0 = (tid & 7) ^ (lrs & 7);
  const int ra = (lrs << 1) | (g0 >> 2);
  const int ko = (g0 & 3) << 3;

  const int lrb = l15 >> 1;
  const int gg = ((l15 & 1) << 2) | l4;
  const int gsw = gg ^ lrb;
  const int aoff = wm * 4096 + lrb * 64 + gsw * 8;
  const int boff = (wn >> 1) * 4096 + (wn & 1) * 2048 + lrb * 64 + gsw * 8;

  f32x4 acc[8][4];
#pragma unroll
  for (int i = 0; i < 8; ++i)
#pragma unroll
    for (int j = 0; j < 4; ++j)
#pragma unroll
      for (int r = 0; r < 4; ++r) acc[i][j][r] = 0.f;

  const int NT = K >> 5;

  auto stA = [&](int sb, int t2) {
    const u16* s0 = Ab + (size_t)(m0 + ra) * K + t2 * 32 + ko;
    const u16* s1 = Ab + (size_t)(m0 + 128 + ra) * K + t2 * 32 + ko;
    gload16(s0, &As[sb][tid * 8]);
    gload16(s1, &As[sb][4096 + tid * 8]);
  };
  auto stB = [&](int sb, int t2) {
    const u16* s0 = Bb + (size_t)(n0 + ra) * K + t2 * 32 + ko;
    const u16* s1 = Bb + (size_t)(n0 + 128 + ra) * K + t2 * 32 + ko;
    gload16(s0, &Bs[sb][tid * 8]);
    gload16(s1, &Bs[sb][4096 + tid * 8]);
  };

#define TILE_BODY(P, TT, DOSTG, WN)                                            \
  do {                                                                         \
    if (DOSTG) { stA(((P) + 3) & 3, (TT) + 3); stB(((P) + 3) & 3, (TT) + 3); } \
    bf16x8 bq[4], af0[4], af1[4];                                              \
    _Pragma("unroll") for (int ni = 0; ni < 4; ++ni)                           \
        bq[ni] = *(const bf16x8*)&Bs[P][boff + ni * 512];                      \
    _Pragma("unroll") for (int i = 0; i < 4; ++i)                              \
        af0[i] = *(const bf16x8*)&As[P][aoff + i * 512];                       \
    _Pragma("unroll") for (int i = 0; i < 4; ++i)                              \
        af1[i] = *(const bf16x8*)&As[P][aoff + 2048 + i * 512];                \
    __builtin_amdgcn_s_setprio(1);                                             \
    _Pragma("unroll") for (int i = 0; i < 4; ++i)                              \
        _Pragma("unroll") for (int ni = 0; ni < 4; ++ni)                       \
            acc[i][ni] = __builtin_amdgcn_mfma_f32_16x16x32_bf16(              \
                af0[i], bq[ni], acc[i][ni], 0, 0, 0);                          \
    _Pragma("unroll") for (int i = 0; i < 4; ++i)                              \
        _Pragma("unroll") for (int ni = 0; ni < 4; ++ni)                       \
            acc[4 + i][ni] = __builtin_amdgcn_mfma_f32_16x16x32_bf16(          \
                af1[i], bq[ni], acc[4 + i][ni], 0, 0, 0);                      \
    __builtin_amdgcn_s_setprio(0);                                             \
    if ((WN) == 8) asm volatile("s_waitcnt vmcnt(8)" ::: "memory");            \
    else if ((WN) == 4) asm volatile("s_waitcnt vmcnt(4)" ::: "memory");       \
    else if ((WN) == 0) asm volatile("s_waitcnt vmcnt(0)" ::: "memory");       \
    if ((WN) >= -1) __builtin_amdgcn_s_barrier();                              \
  } while (0)

  stA(0, 0); stB(0, 0);
  stA(1, 1); stB(1, 1);
  stA(2, 2); stB(2, 2);
  asm volatile("s_waitcnt vmcnt(8)" ::: "memory");
  __builtin_amdgcn_s_barrier();

  int t = 0;
  for (; t + 7 < NT; t += 4) {
    TILE_BODY(0, t, 1, 8);
    TILE_BODY(1, t + 1, 1, 8);
    TILE_BODY(2, t + 2, 1, 8);
    TILE_BODY(3, t + 3, 1, 8);
  }
  TILE_BODY(0, t, 1, 8);
  TILE_BODY(1, t + 1, 0, 4);
  TILE_BODY(2, t + 2, 0, 0);
  TILE_BODY(3, t + 3, 0, -2);

#undef TILE_BODY

  if (EPI == 0) {
#pragma unroll
    for (int mi = 0; mi < 8; ++mi) {
#pragma unroll
      for (int ni = 0; ni < 4; ++ni) {
        const int gr0 = m0 + wm * 128 + mi * 16 + l4 * 4;
        const int gc = n0 + wn * 64 + ni * 16 + l15;
        const int bsel = gc >> 9, cin = gc & 511;
        const float bs = bias[gc];
        if (bsel < 2) {
          u16* dst = bsel ? kb : qb;
#pragma unroll
          for (int r = 0; r < 4; ++r) {
            float vvv = acc[mi][ni][r] + bs;
            if (bsel == 0) vvv *= QSCALE;
            dst[(size_t)(gr0 + r) * 512 + cin] = f2bf(vvv);
          }
        } else {
          ushort4 o;
          o.x = f2bf(acc[mi][ni][0] + bs);
          o.y = f2bf(acc[mi][ni][1] + bs);
          o.z = f2bf(acc[mi][ni][2] + bs);
          o.w = f2bf(acc[mi][ni][3] + bs);
          const int bb = gr0 >> 10, p = gr0 & 1023;
          *(ushort4*)&vt[(size_t)bb * 524288 + (size_t)cin * 1024 + p] = o;
        }
      }
    }
  } else {  // EPI == 2
#pragma unroll
    for (int mi = 0; mi < 8; ++mi) {
#pragma unroll
      for (int ni = 0; ni < 4; ++ni) {
        const int gr0 = m0 + wm * 128 + mi * 16 + l4 * 4;
        const int gc = n0 + wn * 64 + ni * 16 + l15;
#pragma unroll
        for (int r = 0; r < 4; ++r)
          outf[(size_t)(gr0 + r) * N + gc] =
              acc[mi][ni][r] + bias[gc] + resid[(size_t)(gr0 + r) * N + gc];
      }
    }
  }
}

// ---------------------------------------------------------------------------
// Fused flash attention (no-max softmax): O = (exp(q@k^T) @ V) / rowsum.
// Grid 256 = 32 batches x 8 q-blocks(128 rows); 512 thr = 8 waves, ALL-M
// split (wave owns 16 q-rows, full 512-d output -> oacc f32x4[32] = 128 VGPR).
// Q held in regs (16 kfrags, 64 VGPR).  kv-tiles of 32, NT=32:
//   - K-tile [32][512] LDS dbuf, gload16-staged with granule-XOR swizzle
//     (g' low3 ^= kvrow&7; proven algebra from the ring GEMM) -> 2-way free.
//   - V-tile reg-staged from vt[z][d][p] into padded LDS [512][40] dbuf.
//   - S = mfma(qf, K-frags): per wave [16q x 32kv]; exp -> per-wave-private
//     P-buf [16][40] (no barrier needed); lane-local rsum accumulation.
//   - PV: A = P-frag (1 b128, own wave), B = 32 V-frags, 32 MFMA.
// One __syncthreads per tile.  Row-sum finalized with 4 shfl_xor; O scaled
// and stored bf16 rowmajor.  No S materialization, no lsum.
// ---------------------------------------------------------------------------
__global__ __launch_bounds__(512, 2) void flash_k(
    const u16* __restrict__ qg, const u16* __restrict__ kg,
    const u16* __restrict__ vtg, u16* __restrict__ Og) {
  __shared__ u16 Ks[2][32 * 512];   // 2 x 32 KB
  __shared__ u16 Vs[2][512 * 40];   // 2 x 40 KB (padded stride 40)
  __shared__ u16 Ps[8][16 * 40];    // per-wave P buffer (10 KB)

  const int tid = threadIdx.x, lane = tid & 63, wid = tid >> 6;
  const int l15 = lane & 15, l4 = lane >> 4;
  const int orig = blockIdx.x;
  const int xcd = orig & 7, jj = orig >> 3;
  const int z = xcd * 4 + (jj & 3);   // batch pinned to XCD (K/V L2-resident)
  const int qb0 = jj >> 2;            // q-block 0..7

  const u16* qz = qg + (size_t)(z * 1024 + qb0 * 128) * 512;
  const u16* kz = kg + (size_t)z * 1024 * 512;
  const u16* vz = vtg + (size_t)z * 512 * 1024;

  // K staging map: sweep s covers rows s*8+(tid>>6); row&7 == tid>>6
  const int krow_ = tid >> 6;
  const int kgr = tid & 63;
  const int kgs = (kgr & 56) | ((kgr & 7) ^ (krow_ & 7));  // pre-swizzled src granule
  // V staging map: sweep s covers rows s*128+(tid>>2), kv granule (tid&3)*8
  const int vrow_ = tid >> 2;
  const int vkvg = (tid & 3) << 3;

  auto stageK = [&](int t, int buf) {
    const u16* src = kz + ((size_t)t * 32 + krow_) * 512 + kgs * 8;
#pragma unroll
    for (int s = 0; s < 4; ++s)
      gload16(src + (size_t)s * 8 * 512, &Ks[buf][s * 4096 + tid * 8]);
  };

  bf16x8 vstg[4];
  auto loadV = [&](int t) {
#pragma unroll
    for (int s = 0; s < 4; ++s)
      vstg[s] = *(const bf16x8*)&vz[(size_t)(s * 128 + vrow_) * 1024 + t * 32 + vkvg];
  };
  auto writeV = [&](int buf) {
#pragma unroll
    for (int s = 0; s < 4; ++s)
      *(bf16x8*)&Vs[buf][(s * 128 + vrow_) * 40 + vkvg] = vstg[s];
  };

  // Q fragments: wave's 16 q-rows x 512 k, 16 frags (64 VGPR)
  bf16x8 qf[16];
#pragma unroll
  for (int kf = 0; kf < 16; ++kf)
    qf[kf] = *(const bf16x8*)&qz[(size_t)(wid * 16 + l15) * 512 + kf * 32 + l4 * 8];

  f32x4 oacc[32];
#pragma unroll
  for (int i = 0; i < 32; ++i)
#pragma unroll
    for (int r = 0; r < 4; ++r) oacc[i][r] = 0.f;
  float rsum[4] = {0.f, 0.f, 0.f, 0.f};

  // prologue: tile 0
  stageK(0, 0);
  loadV(0);
  writeV(0);          // compiler waits vstg deps
  __syncthreads();    // drains K gloads, publishes V

  for (int t = 0; t < 32; ++t) {
    const int cur = t & 1;
    const bool pre = (t + 1 < 32);
    if (pre) { stageK(t + 1, cur ^ 1); loadV(t + 1); }

    // S = q @ k^T for this kv-tile: [16 q][32 kv] per wave
    f32x4 sacc[2];
#pragma unroll
    for (int nf = 0; nf < 2; ++nf)
#pragma unroll
      for (int r = 0; r < 4; ++r) sacc[nf][r] = 0.f;
#pragma unroll
    for (int kf = 0; kf < 16; ++kf) {
#pragma unroll
      for (int nf = 0; nf < 2; ++nf) {
        const int kvr = nf * 16 + l15;
        const int g = kf * 4 + l4;
        const int gs = (g & 56) | ((g & 7) ^ (kvr & 7));
        const bf16x8 bfr = *(const bf16x8*)&Ks[cur][kvr * 512 + gs * 8];
        sacc[nf] = __builtin_amdgcn_mfma_f32_16x16x32_bf16(qf[kf], bfr, sacc[nf], 0, 0, 0);
      }
    }

    // exp -> per-wave P buffer + lane-local row-sum partials
#pragma unroll
    for (int nf = 0; nf < 2; ++nf)
#pragma unroll
      for (int r = 0; r < 4; ++r) {
        const float e = __expf(sacc[nf][r]);
        rsum[r] += e;
        Ps[wid][(l4 * 4 + r) * 40 + nf * 16 + l15] = f2bf(e);
      }

    if (pre) writeV(cur ^ 1);  // V(t+1) regs -> LDS (published at end barrier)

    // PV: O[16 q][512 d] += P[16 q][32 kv] @ V[32 kv][512 d]
    const bf16x8 pa = *(const bf16x8*)&Ps[wid][l15 * 40 + l4 * 8];
    __builtin_amdgcn_s_setprio(1);
#pragma unroll
    for (int nf = 0; nf < 32; ++nf) {
      const bf16x8 vb = *(const bf16x8*)&Vs[cur][(nf * 16 + l15) * 40 + l4 * 8];
      oacc[nf] = __builtin_amdgcn_mfma_f32_16x16x32_bf16(pa, vb, oacc[nf], 0, 0, 0);
    }
    __builtin_amdgcn_s_setprio(0);
    __syncthreads();
  }

  // finalize row sums (reduce over the 16-lane l15 group) and store O
#pragma unroll
  for (int r = 0; r < 4; ++r) {
    float v = rsum[r];
    v += __shfl_xor(v, 1);
    v += __shfl_xor(v, 2);
    v += __shfl_xor(v, 4);
    v += __shfl_xor(v, 8);
    rsum[r] = 1.0f / v;
  }
  u16* orow = Og + (size_t)(z * 1024 + qb0 * 128 + wid * 16) * 512;
#pragma unroll
  for (int nf = 0; nf < 32; ++nf)
#pragma unroll
    for (int r = 0; r < 4; ++r)
      orow[(size_t)(l4 * 4 + r) * 512 + nf * 16 + l15] =
          f2bf(oacc[nf][r] * rsum[r]);
}

// ---------------------------------------------------------------------------
extern "C" void kernel_launch(void* const* d_in, const int* in_sizes, int n_in,
                              void* d_out, int out_size, void* d_ws, size_t ws_size,
                              hipStream_t stream) {
  const float* x = (const float*)d_in[0];
  const float* gn_scale = (const float*)d_in[2];
  const float* gn_bias = (const float*)d_in[3];
  const float* w_qkv = (const float*)d_in[4];
  const float* b_qkv = (const float*)d_in[5];
  const float* w_out = (const float*)d_in[6];
  const float* b_out = (const float*)d_in[7];
  float* out = (float*)d_out;

  char* ws = (char*)d_ws;
  const size_t MB = 1024ull * 1024ull;
  u16* qb = (u16*)(ws + 0 * MB);      // 32 MB  [32768][512]
  u16* kb = (u16*)(ws + 32 * MB);     // 32 MB  [32768][512]
  u16* vt = (u16*)(ws + 64 * MB);     // 32 MB  [32][512][1024]  (V transposed)
  u16* zO = (u16*)(ws + 128 * MB);    // 32 MB  z, later reused as O
  u16* wqkvT = (u16*)(ws + 224 * MB); // 1.5 MB [1536][512]
  u16* woutT = (u16*)(ws + 226 * MB); // 0.5 MB [512][512]

  prep_weights<<<4096, 256, 0, stream>>>(w_qkv, w_out, wqkvT, woutT);
  groupnorm_k<<<1024, 256, 0, stream>>>(x, gn_scale, gn_bias, zO);

  // QKV: z @ wqkvT^T -> q,k (rowmajor, q scaled), v (transposed)
  gemm_ring<0><<<768, 512, 0, stream>>>(
      zO, wqkvT, 6, 768, 1536, 512, 0, 16, 0, 0, 0, 0, b_qkv, nullptr,
      qb, kb, vt, nullptr, nullptr);

  // Fused attention: O = (exp(q k^T) V) / rowsum   (writes zO)
  flash_k<<<256, 512, 0, stream>>>(qb, kb, vt, zO);

  // out = O @ w_out^T + b_out + x
  gemm_ring<2><<<256, 512, 0, stream>>>(
      zO, woutT, 2, 256, 512, 512, 0, 16, 0, 0, 0, 0, b_out, x,
      nullptr, nullptr, nullptr, nullptr, out);
}

// Round 11
// 235.981 us; speedup vs baseline: 1.2702x; 1.0930x over previous
//
#include <hip/hip_runtime.h>

typedef unsigned short u16;
typedef short bf16x8 __attribute__((ext_vector_type(8)));
typedef float f32x4 __attribute__((ext_vector_type(4)));

__device__ __forceinline__ u16 f2bf(float f) {
  union { float f; unsigned u; } c; c.f = f;
  unsigned r = (c.u + 0x7FFFu + ((c.u >> 16) & 1u)) >> 16;
  return (u16)r;
}
__device__ __forceinline__ float bf2f(u16 h) {
  union { unsigned u; float f; } c; c.u = ((unsigned)h) << 16;
  return c.f;
}
__device__ __forceinline__ void gload16(const void* g, void* l) {
  __builtin_amdgcn_global_load_lds(
      (const __attribute__((address_space(1))) unsigned*)g,
      (__attribute__((address_space(3))) unsigned*)l, 16, 0, 0);
}

// ---------------------------------------------------------------------------
// Weight prep: w_qkv [512,1536] -> wqkvT bf16 [1536,512]; w_out -> woutT [512,512]
// ---------------------------------------------------------------------------
__global__ __launch_bounds__(256) void prep_weights(
    const float* __restrict__ w_qkv, const float* __restrict__ w_out,
    u16* __restrict__ wqkvT, u16* __restrict__ woutT) {
  int i = blockIdx.x * 256 + threadIdx.x;
  const int T1 = 1536 * 512;
  if (i < T1) {
    int n = i >> 9, c = i & 511;
    wqkvT[i] = f2bf(w_qkv[(size_t)c * 1536 + n]);
  } else {
    int j = i - T1;
    int n = j >> 9, c = j & 511;
    woutT[j] = f2bf(w_out[(size_t)c * 512 + n]);
  }
}

// ---------------------------------------------------------------------------
// GroupNorm: x fp32 [32,1024,512] -> z bf16; 32 groups of 16 ch
// ---------------------------------------------------------------------------
__global__ __launch_bounds__(256) void groupnorm_k(
    const float* __restrict__ x, const float* __restrict__ scale,
    const float* __restrict__ bias, u16* __restrict__ z) {
  const int blk = blockIdx.x, b = blk >> 5, g = blk & 31;
  const float* xb = x + (size_t)b * 524288 + g * 16;
  u16* zb = z + (size_t)b * 524288 + g * 16;
  const int tid = threadIdx.x, lane = tid & 63, wid = tid >> 6;

  float4 vv[16];
  float s = 0.f, ss = 0.f;
#pragma unroll
  for (int i = 0; i < 16; ++i) {
    int e = (i * 256 + tid) * 4;
    int hw = e >> 4, j = e & 15;
    vv[i] = *(const float4*)&xb[(size_t)hw * 512 + j];
    s += vv[i].x + vv[i].y + vv[i].z + vv[i].w;
    ss += vv[i].x * vv[i].x + vv[i].y * vv[i].y + vv[i].z * vv[i].z + vv[i].w * vv[i].w;
  }
#pragma unroll
  for (int off = 32; off; off >>= 1) {
    s += __shfl_xor(s, off);
    ss += __shfl_xor(ss, off);
  }
  __shared__ float rs[4], rq[4];
  if (!lane) { rs[wid] = s; rq[wid] = ss; }
  __syncthreads();
  float S_ = rs[0] + rs[1] + rs[2] + rs[3];
  float Q_ = rq[0] + rq[1] + rq[2] + rq[3];
  const float inv_n = 1.f / 16384.f;
  float mean = S_ * inv_n;
  float var = Q_ * inv_n - mean * mean;
  float rstd = rsqrtf(var + 1e-5f);

  int j0 = (tid * 4) & 15;
  float sc0 = scale[g * 16 + j0 + 0] * rstd, sc1 = scale[g * 16 + j0 + 1] * rstd;
  float sc2 = scale[g * 16 + j0 + 2] * rstd, sc3 = scale[g * 16 + j0 + 3] * rstd;
  float bi0 = bias[g * 16 + j0 + 0] - mean * sc0, bi1 = bias[g * 16 + j0 + 1] - mean * sc1;
  float bi2 = bias[g * 16 + j0 + 2] - mean * sc2, bi3 = bias[g * 16 + j0 + 3] - mean * sc3;
#pragma unroll
  for (int i = 0; i < 16; ++i) {
    int e = (i * 256 + tid) * 4;
    int hw = e >> 4, j = e & 15;
    ushort4 o;
    o.x = f2bf(vv[i].x * sc0 + bi0);
    o.y = f2bf(vv[i].y * sc1 + bi1);
    o.z = f2bf(vv[i].z * sc2 + bi2);
    o.w = f2bf(vv[i].w * sc3 + bi3);
    *(ushort4*)&zb[(size_t)hw * 512 + j] = o;
  }
}

// ---------------------------------------------------------------------------
// Deep-ring GEMM (round-9, unchanged): 256x256 tile, BK=32, 4-buffer ring,
// 1 barrier + counted vmcnt(8) per tile.
// EPI 0: q,k rowmajor (+bias, q scaled), v -> TRANSPOSED [b][c][p]
// EPI 2: fp32 +bias+resid
// ---------------------------------------------------------------------------
#define QSCALE 0.04419417382415922f

template <int EPI>
__global__ __launch_bounds__(512, 2) void gemm_ring(
    const u16* __restrict__ A, const u16* __restrict__ Bt,
    int gx, int gxy, int N, int K,
    int sched, int sp1, int sp2,
    long long sAb, long long sBb, long long sCb,
    const float* __restrict__ bias, const float* __restrict__ resid,
    u16* __restrict__ qb, u16* __restrict__ kb, u16* __restrict__ vt,
    u16* __restrict__ outb, float* __restrict__ outf) {
  const int orig = blockIdx.x;
  const int xcd = orig & 7, jj = orig >> 3;
  int id;
  if (sched == 0) {
    int pan = jj % gx, loc = jj / gx;
    id = (xcd * sp1 + loc) * gx + pan;
  } else {
    int tile = jj % gxy, bl = jj / gxy;
    id = (xcd * sp2 + bl) * gxy + tile;
  }
  const int z = id / gxy;
  const int r2 = id - z * gxy;
  const int by = r2 / gx, bx = r2 - by * gx;

  const u16* Ab = A + (size_t)z * sAb;
  const u16* Bb = Bt + (size_t)z * sBb;

  __shared__ u16 As[4][8192];
  __shared__ u16 Bs[4][8192];

  const int tid = threadIdx.x;
  const int lane = tid & 63, wid = tid >> 6;
  const int wm = wid & 1, wn = wid >> 1;
  const int l15 = lane & 15, l4 = lane >> 4;
  const int m0 = by * 256, n0 = bx * 256;

  const int lrs = tid >> 3;
  const int g0 = (tid & 7) ^ (lrs & 7);
  const int ra = (lrs << 1) | (g0 >> 2);
  const int ko = (g0 & 3) << 3;

  const int lrb = l15 >> 1;
  const int gg = ((l15 & 1) << 2) | l4;
  const int gsw = gg ^ lrb;
  const int aoff = wm * 4096 + lrb * 64 + gsw * 8;
  const int boff = (wn >> 1) * 4096 + (wn & 1) * 2048 + lrb * 64 + gsw * 8;

  f32x4 acc[8][4];
#pragma unroll
  for (int i = 0; i < 8; ++i)
#pragma unroll
    for (int j = 0; j < 4; ++j)
#pragma unroll
      for (int r = 0; r < 4; ++r) acc[i][j][r] = 0.f;

  const int NT = K >> 5;

  auto stA = [&](int sb, int t2) {
    const u16* s0 = Ab + (size_t)(m0 + ra) * K + t2 * 32 + ko;
    const u16* s1 = Ab + (size_t)(m0 + 128 + ra) * K + t2 * 32 + ko;
    gload16(s0, &As[sb][tid * 8]);
    gload16(s1, &As[sb][4096 + tid * 8]);
  };
  auto stB = [&](int sb, int t2) {
    const u16* s0 = Bb + (size_t)(n0 + ra) * K + t2 * 32 + ko;
    const u16* s1 = Bb + (size_t)(n0 + 128 + ra) * K + t2 * 32 + ko;
    gload16(s0, &Bs[sb][tid * 8]);
    gload16(s1, &Bs[sb][4096 + tid * 8]);
  };

#define TILE_BODY(P, TT, DOSTG, WN)                                            \
  do {                                                                         \
    if (DOSTG) { stA(((P) + 3) & 3, (TT) + 3); stB(((P) + 3) & 3, (TT) + 3); } \
    bf16x8 bq[4], af0[4], af1[4];                                              \
    _Pragma("unroll") for (int ni = 0; ni < 4; ++ni)                           \
        bq[ni] = *(const bf16x8*)&Bs[P][boff + ni * 512];                      \
    _Pragma("unroll") for (int i = 0; i < 4; ++i)                              \
        af0[i] = *(const bf16x8*)&As[P][aoff + i * 512];                       \
    _Pragma("unroll") for (int i = 0; i < 4; ++i)                              \
        af1[i] = *(const bf16x8*)&As[P][aoff + 2048 + i * 512];                \
    __builtin_amdgcn_s_setprio(1);                                             \
    _Pragma("unroll") for (int i = 0; i < 4; ++i)                              \
        _Pragma("unroll") for (int ni = 0; ni < 4; ++ni)                       \
            acc[i][ni] = __builtin_amdgcn_mfma_f32_16x16x32_bf16(              \
                af0[i], bq[ni], acc[i][ni], 0, 0, 0);                          \
    _Pragma("unroll") for (int i = 0; i < 4; ++i)                              \
        _Pragma("unroll") for (int ni = 0; ni < 4; ++ni)                       \
            acc[4 + i][ni] = __builtin_amdgcn_mfma_f32_16x16x32_bf16(          \
                af1[i], bq[ni], acc[4 + i][ni], 0, 0, 0);                      \
    __builtin_amdgcn_s_setprio(0);                                             \
    if ((WN) == 8) asm volatile("s_waitcnt vmcnt(8)" ::: "memory");            \
    else if ((WN) == 4) asm volatile("s_waitcnt vmcnt(4)" ::: "memory");       \
    else if ((WN) == 0) asm volatile("s_waitcnt vmcnt(0)" ::: "memory");       \
    if ((WN) >= -1) __builtin_amdgcn_s_barrier();                              \
  } while (0)

  stA(0, 0); stB(0, 0);
  stA(1, 1); stB(1, 1);
  stA(2, 2); stB(2, 2);
  asm volatile("s_waitcnt vmcnt(8)" ::: "memory");
  __builtin_amdgcn_s_barrier();

  int t = 0;
  for (; t + 7 < NT; t += 4) {
    TILE_BODY(0, t, 1, 8);
    TILE_BODY(1, t + 1, 1, 8);
    TILE_BODY(2, t + 2, 1, 8);
    TILE_BODY(3, t + 3, 1, 8);
  }
  TILE_BODY(0, t, 1, 8);
  TILE_BODY(1, t + 1, 0, 4);
  TILE_BODY(2, t + 2, 0, 0);
  TILE_BODY(3, t + 3, 0, -2);

#undef TILE_BODY

  if (EPI == 0) {
#pragma unroll
    for (int mi = 0; mi < 8; ++mi) {
#pragma unroll
      for (int ni = 0; ni < 4; ++ni) {
        const int gr0 = m0 + wm * 128 + mi * 16 + l4 * 4;
        const int gc = n0 + wn * 64 + ni * 16 + l15;
        const int bsel = gc >> 9, cin = gc & 511;
        const float bs = bias[gc];
        if (bsel < 2) {
          u16* dst = bsel ? kb : qb;
#pragma unroll
          for (int r = 0; r < 4; ++r) {
            float vvv = acc[mi][ni][r] + bs;
            if (bsel == 0) vvv *= QSCALE;
            dst[(size_t)(gr0 + r) * 512 + cin] = f2bf(vvv);
          }
        } else {
          ushort4 o;
          o.x = f2bf(acc[mi][ni][0] + bs);
          o.y = f2bf(acc[mi][ni][1] + bs);
          o.z = f2bf(acc[mi][ni][2] + bs);
          o.w = f2bf(acc[mi][ni][3] + bs);
          const int bb = gr0 >> 10, p = gr0 & 1023;
          *(ushort4*)&vt[(size_t)bb * 524288 + (size_t)cin * 1024 + p] = o;
        }
      }
    }
  } else {  // EPI == 2
#pragma unroll
    for (int mi = 0; mi < 8; ++mi) {
#pragma unroll
      for (int ni = 0; ni < 4; ++ni) {
        const int gr0 = m0 + wm * 128 + mi * 16 + l4 * 4;
        const int gc = n0 + wn * 64 + ni * 16 + l15;
#pragma unroll
        for (int r = 0; r < 4; ++r)
          outf[(size_t)(gr0 + r) * N + gc] =
              acc[mi][ni][r] + bias[gc] + resid[(size_t)(gr0 + r) * N + gc];
      }
    }
  }
}

// ---------------------------------------------------------------------------
// Fused flash attention v2 (no-max softmax): O = (exp(q@k^T) @ V) / rowsum.
// Grid 256 = 32 batches x 8 q-blocks(128 rows); 512 thr = 8 waves.
// QK: wave owns 16 q-rows (Q in regs, 64 VGPR): S[16q x 32kv], 32 MFMA,
//     32 swizzled Ks reads. exp -> SHARED P dbuf [2][128][40] + lane rsum.
// PV (d-split for fragment reuse): wave owns d-slice [wid*64, +64) over ALL
//     128 q: 8 P-frag reads + V from REGISTERS (4 frags direct from L2-hot
//     vt[z][d][p], prefetched 1 tile ahead) -> 32 MFMA, NO V LDS round-trip.
// One barrier/tile (publishes P[cur] + K DMA for t+1, vmcnt(4) counted).
// LDS/wave-tile: 40 b128 reads + 16 u16 stores (was 65 + 20) ~= MFMA time.
// Row-sums: lane-local across tiles; published once via rsumS[128] at end.
// ---------------------------------------------------------------------------
__global__ __launch_bounds__(512, 2) void flash_k(
    const u16* __restrict__ qg, const u16* __restrict__ kg,
    const u16* __restrict__ vtg, u16* __restrict__ Og) {
  __shared__ u16 Ks[2][32 * 512];   // 64 KB
  __shared__ u16 Ps[2][128 * 40];   // 20 KB (stride 40 u16 = 80B, bank-clean)
  __shared__ float rsumS[128];

  const int tid = threadIdx.x, lane = tid & 63, wid = tid >> 6;
  const int l15 = lane & 15, l4 = lane >> 4;
  const int orig = blockIdx.x;
  const int xcd = orig & 7, jj = orig >> 3;
  const int z = xcd * 4 + (jj & 3);   // batch pinned to XCD
  const int qb0 = jj >> 2;            // q-block 0..7

  const u16* qz = qg + (size_t)(z * 1024 + qb0 * 128) * 512;
  const u16* kz = kg + (size_t)z * 1024 * 512;
  const u16* vz = vtg + (size_t)z * 512 * 1024;

  // K staging: granule-XOR pre-swizzled source (read swizzle matches)
  const int krow_ = tid >> 6;
  const int kgr = tid & 63;
  const int kgs = (kgr & 56) | ((kgr & 7) ^ (krow_ & 7));

  auto stageK = [&](int t, int buf) {
    const u16* src = kz + ((size_t)t * 32 + krow_) * 512 + kgs * 8;
#pragma unroll
    for (int s = 0; s < 4; ++s)
      gload16(src + (size_t)s * 8 * 512, &Ks[buf][s * 4096 + tid * 8]);
  };

  // V d-slice direct-to-register (wave owns d in [wid*64, wid*64+64))
  const int dbase = wid * 64;
  bf16x8 vcur[4], vnxt[4];
  auto loadV = [&](int t, bf16x8* dst) {
#pragma unroll
    for (int nf = 0; nf < 4; ++nf)
      dst[nf] = *(const bf16x8*)&vz[(size_t)(dbase + nf * 16 + l15) * 1024 + t * 32 + l4 * 8];
  };

  // Q fragments: wave's 16 q-rows x 512 k (64 VGPR)
  bf16x8 qf[16];
#pragma unroll
  for (int kf = 0; kf < 16; ++kf)
    qf[kf] = *(const bf16x8*)&qz[(size_t)(wid * 16 + l15) * 512 + kf * 32 + l4 * 8];

  f32x4 oacc[8][4];   // O slice [128 q][64 d]: [mi][nf]
#pragma unroll
  for (int i = 0; i < 8; ++i)
#pragma unroll
    for (int j = 0; j < 4; ++j)
#pragma unroll
      for (int r = 0; r < 4; ++r) oacc[i][j][r] = 0.f;
  float rsum[4] = {0.f, 0.f, 0.f, 0.f};

  // prologue
  stageK(0, 0);
  loadV(0, vcur);
  asm volatile("s_waitcnt vmcnt(4)" ::: "memory");  // K(0) done; V(0) by dep
  __builtin_amdgcn_s_barrier();

  for (int t = 0; t < 32; ++t) {
    const int cur = t & 1;
    const bool pre = (t + 1 < 32);
    if (pre) { stageK(t + 1, cur ^ 1); loadV(t + 1, vnxt); }

    // QK: S[16q x 32kv] for this wave's q-rows
    f32x4 sacc[2];
#pragma unroll
    for (int nf = 0; nf < 2; ++nf)
#pragma unroll
      for (int r = 0; r < 4; ++r) sacc[nf][r] = 0.f;
#pragma unroll
    for (int kf = 0; kf < 16; ++kf) {
#pragma unroll
      for (int nf = 0; nf < 2; ++nf) {
        const int kvr = nf * 16 + l15;
        const int g = kf * 4 + l4;
        const int gs = (g & 56) | ((g & 7) ^ (kvr & 7));
        const bf16x8 bfr = *(const bf16x8*)&Ks[cur][kvr * 512 + gs * 8];
        sacc[nf] = __builtin_amdgcn_mfma_f32_16x16x32_bf16(qf[kf], bfr, sacc[nf], 0, 0, 0);
      }
    }

    // exp -> shared P[cur] + lane-local row-sum partials
#pragma unroll
    for (int nf = 0; nf < 2; ++nf)
#pragma unroll
      for (int r = 0; r < 4; ++r) {
        const float e = __expf(sacc[nf][r]);
        rsum[r] += e;
        Ps[cur][(wid * 16 + l4 * 4 + r) * 40 + nf * 16 + l15] = f2bf(e);
      }

    if (pre) asm volatile("s_waitcnt vmcnt(4)" ::: "memory");  // K(t+1) landed
    __builtin_amdgcn_s_barrier();   // publish P[cur] + Ks[cur^1]

    // PV: O[128q x 64d-slice] += P[cur] @ V(regs)
    __builtin_amdgcn_s_setprio(1);
#pragma unroll
    for (int mi = 0; mi < 8; ++mi) {
      const bf16x8 pa = *(const bf16x8*)&Ps[cur][(mi * 16 + l15) * 40 + l4 * 8];
#pragma unroll
      for (int nf = 0; nf < 4; ++nf)
        oacc[mi][nf] = __builtin_amdgcn_mfma_f32_16x16x32_bf16(pa, vcur[nf], oacc[mi][nf], 0, 0, 0);
    }
    __builtin_amdgcn_s_setprio(0);

    if (pre) {
#pragma unroll
      for (int nf = 0; nf < 4; ++nf) vcur[nf] = vnxt[nf];
    }
  }

  // publish per-row inverse sums
#pragma unroll
  for (int r = 0; r < 4; ++r) {
    float v = rsum[r];
    v += __shfl_xor(v, 1);
    v += __shfl_xor(v, 2);
    v += __shfl_xor(v, 4);
    v += __shfl_xor(v, 8);
    if (l15 == 0) rsumS[wid * 16 + l4 * 4 + r] = 1.0f / v;
  }
  __syncthreads();

  // store O slice scaled by 1/rowsum
  u16* ob = Og + (size_t)(z * 1024 + qb0 * 128) * 512;
#pragma unroll
  for (int mi = 0; mi < 8; ++mi) {
#pragma unroll
    for (int r = 0; r < 4; ++r) {
      const int q = mi * 16 + l4 * 4 + r;
      const float inv = rsumS[q];
#pragma unroll
      for (int nf = 0; nf < 4; ++nf)
        ob[(size_t)q * 512 + dbase + nf * 16 + l15] = f2bf(oacc[mi][nf][r] * inv);
    }
  }
}

// ---------------------------------------------------------------------------
extern "C" void kernel_launch(void* const* d_in, const int* in_sizes, int n_in,
                              void* d_out, int out_size, void* d_ws, size_t ws_size,
                              hipStream_t stream) {
  const float* x = (const float*)d_in[0];
  const float* gn_scale = (const float*)d_in[2];
  const float* gn_bias = (const float*)d_in[3];
  const float* w_qkv = (const float*)d_in[4];
  const float* b_qkv = (const float*)d_in[5];
  const float* w_out = (const float*)d_in[6];
  const float* b_out = (const float*)d_in[7];
  float* out = (float*)d_out;

  char* ws = (char*)d_ws;
  const size_t MB = 1024ull * 1024ull;
  u16* qb = (u16*)(ws + 0 * MB);      // 32 MB  [32768][512]
  u16* kb = (u16*)(ws + 32 * MB);     // 32 MB  [32768][512]
  u16* vt = (u16*)(ws + 64 * MB);     // 32 MB  [32][512][1024]  (V transposed)
  u16* zO = (u16*)(ws + 128 * MB);    // 32 MB  z, later reused as O
  u16* wqkvT = (u16*)(ws + 224 * MB); // 1.5 MB [1536][512]
  u16* woutT = (u16*)(ws + 226 * MB); // 0.5 MB [512][512]

  prep_weights<<<4096, 256, 0, stream>>>(w_qkv, w_out, wqkvT, woutT);
  groupnorm_k<<<1024, 256, 0, stream>>>(x, gn_scale, gn_bias, zO);

  // QKV: z @ wqkvT^T -> q,k (rowmajor, q scaled), v (transposed)
  gemm_ring<0><<<768, 512, 0, stream>>>(
      zO, wqkvT, 6, 768, 1536, 512, 0, 16, 0, 0, 0, 0, b_qkv, nullptr,
      qb, kb, vt, nullptr, nullptr);

  // Fused attention: O = (exp(q k^T) V) / rowsum   (writes zO)
  flash_k<<<256, 512, 0, stream>>>(qb, kb, vt, zO);

  // out = O @ w_out^T + b_out + x
  gemm_ring<2><<<256, 512, 0, stream>>>(
      zO, woutT, 2, 256, 512, 512, 0, 16, 0, 0, 0, 0, b_out, x,
      nullptr, nullptr, nullptr, nullptr, out);
}